// Round 11
// baseline (1540.957 us; speedup 1.0000x reference)
//
#include <hip/hip_runtime.h>

#define EPS 1e-5f

typedef __attribute__((ext_vector_type(8)))  short short8;
typedef __attribute__((ext_vector_type(16))) float f32x16;
typedef __attribute__((ext_vector_type(4)))  unsigned u32x4;

__device__ inline unsigned f2bf(float f) {
    unsigned u = __builtin_bit_cast(unsigned, f);
    return (u + 0x7fffu + ((u >> 16) & 1u)) >> 16;   // RNE f32->bf16
}
__device__ inline float bchi(unsigned u) {           // high-bf16 -> f32
    return __builtin_bit_cast(float, u & 0xffff0000u);
}
__device__ inline float bclo(unsigned u) {           // low-bf16 -> f32
    return __builtin_bit_cast(float, u << 16);
}

// prep: three regions of d_ws
//  [0)      w2f:  bf16 w2 in mfma_f32_32x32x16_bf16 B-frag order
//           w2f[nf*8192 + ks*512 + lane*8 + e] = bf16(w2[ks*16+(lane>>5)*8+e][nf*32+(lane&31)])
//  [131072) embp: (emb + b2) as bf16 pairs: embp[row*128+g*32+c] =
//           pack(bf16(e[row][g*64+c]), bf16(e[row][g*64+32+c]))
//  [182272) w1q:  per-col packed bf16 {w1_0,w1_1,w1_2,b1}: w1q[2c]=pack(w1[0][c],w1[1][c]),
//           w1q[2c+1]=pack(w1[2][c], b1[c])
__global__ void prep(const float* __restrict__ w2, const float* __restrict__ emb,
                     const float* __restrict__ b2, const float* __restrict__ w1,
                     const float* __restrict__ b1,
                     unsigned short* __restrict__ w2f, unsigned* __restrict__ embp,
                     unsigned* __restrict__ w1q) {
    int idx = blockIdx.x * 256 + threadIdx.x;
    if (idx < 65536) {
        int e    = idx & 7;
        int lane = (idx >> 3) & 63;
        int ks   = (idx >> 9) & 15;
        int nf   = idx >> 13;
        int k    = ks * 16 + ((lane >> 5) << 3) + e;
        int n    = nf * 32 + (lane & 31);
        w2f[idx] = (unsigned short)f2bf(w2[k * 256 + n]);
    } else if (idx < 65536 + 12800) {
        int i   = idx - 65536;
        int row = i >> 7;
        int w   = i & 127;
        int g   = w >> 5;
        int c   = w & 31;
        int clo = g * 64 + c;
        int chi = clo + 32;
        unsigned lo = f2bf(emb[row * 256 + clo] + b2[clo]);
        unsigned hi = f2bf(emb[row * 256 + chi] + b2[chi]);
        embp[i] = lo | (hi << 16);
    } else if (idx < 65536 + 12800 + 256) {
        int c = idx - (65536 + 12800);
        w1q[2 * c]     = f2bf(w1[c])       | (f2bf(w1[256 + c]) << 16);
        w1q[2 * c + 1] = f2bf(w1[512 + c]) | (f2bf(b1[c]) << 16);
    }
}

__device__ inline float scol(unsigned u0, unsigned u1, float x0, float x1, float x2) {
    float t = x0 * bclo(u0) + x1 * bchi(u0) + x2 * bclo(u1) + bchi(u1);
    return t * __builtin_amdgcn_rcpf(1.f + __expf(-t));
}

// LDS-free 32-row tile per wave (64-thread block). Registers are the only
// occupancy limit: acc streamed in two nf-half passes (64 AGPR live) with the
// first half packed to 32 bf16-pair VGPRs -> total ~160 regs -> 3 waves/SIMD.
__global__ __launch_bounds__(64, 3) void fused_kernel(
    const int* __restrict__ z, const float* __restrict__ x,
    const unsigned short* __restrict__ w2f, const unsigned* __restrict__ embp,
    const unsigned* __restrict__ w1q,
    const float* __restrict__ gamma, const float* __restrict__ beta,
    float* __restrict__ out, int N)
{
    const int lane = threadIdx.x & 63;
    const int l31  = lane & 31;
    const int h    = lane >> 5;

    const int t = blockIdx.x;
    const int R = t << 5;

    // own-row inputs (lane pairs l31 / l31+32 duplicate: harmless, broadcast-coalesced)
    const int   zo = z[R + l31];
    const float x0 = x[(R + l31) * 3 + 0];
    const float x1 = x[(R + l31) * 3 + 1];
    const float x2 = x[(R + l31) * 3 + 2];

    f32x16 acc[4];                 // one nf-half (cols pass*128 .. +127): 64 AGPR
    unsigned ph0[16], ph1[16];     // pass-0 result packed bf16 (nf0..3), 32 VGPR

#pragma unroll
    for (int pass = 0; pass < 2; ++pass) {
        // ---- init acc with (emb+b2) gather for this nf-half (C/D layout).
        // z via shfl from the lane owning that row; 32 u32 loads fly early.
#pragma unroll
        for (int j = 0; j < 16; ++j) {
            const int rl = (j & 3) + ((j >> 2) << 3) + (h << 2);
            const int zr = __shfl(zo, rl, 64);
            const unsigned* er = embp + zr * 128 + l31;
            unsigned u0 = er[(pass * 2 + 0) * 32];
            unsigned u1 = er[(pass * 2 + 1) * 32];
            acc[0][j] = bclo(u0); acc[1][j] = bchi(u0);
            acc[2][j] = bclo(u1); acc[3][j] = bchi(u1);
        }

        // ---- K loop: silu directly in A-frag layout (row=l31, k=ks*16+h*8+e),
        // then 4 MFMA into this nf-half. w1q loads are half-wave broadcasts.
#pragma unroll
        for (int ks = 0; ks < 16; ++ks) {
            const unsigned* wqp = w1q + (ks * 16 + h * 8) * 2;
            u32x4 wqa = *(const u32x4*)(wqp);
            u32x4 wqb = *(const u32x4*)(wqp + 4);
            u32x4 wqc = *(const u32x4*)(wqp + 8);
            u32x4 wqd = *(const u32x4*)(wqp + 12);
            u32x4 av;
            av[0] = f2bf(scol(wqa[0], wqa[1], x0, x1, x2)) |
                   (f2bf(scol(wqa[2], wqa[3], x0, x1, x2)) << 16);
            av[1] = f2bf(scol(wqb[0], wqb[1], x0, x1, x2)) |
                   (f2bf(scol(wqb[2], wqb[3], x0, x1, x2)) << 16);
            av[2] = f2bf(scol(wqc[0], wqc[1], x0, x1, x2)) |
                   (f2bf(scol(wqc[2], wqc[3], x0, x1, x2)) << 16);
            av[3] = f2bf(scol(wqd[0], wqd[1], x0, x1, x2)) |
                   (f2bf(scol(wqd[2], wqd[3], x0, x1, x2)) << 16);
            short8 a = __builtin_bit_cast(short8, av);

            const unsigned short* bp = w2f + ks * 512 + lane * 8;
            short8 b0 = *(const short8*)(bp + (pass * 4 + 0) * 8192);
            short8 b1 = *(const short8*)(bp + (pass * 4 + 1) * 8192);
            short8 b2v = *(const short8*)(bp + (pass * 4 + 2) * 8192);
            short8 b3 = *(const short8*)(bp + (pass * 4 + 3) * 8192);
            acc[0] = __builtin_amdgcn_mfma_f32_32x32x16_bf16(a, b0,  acc[0], 0, 0, 0);
            acc[1] = __builtin_amdgcn_mfma_f32_32x32x16_bf16(a, b1,  acc[1], 0, 0, 0);
            acc[2] = __builtin_amdgcn_mfma_f32_32x32x16_bf16(a, b2v, acc[2], 0, 0, 0);
            acc[3] = __builtin_amdgcn_mfma_f32_32x32x16_bf16(a, b3,  acc[3], 0, 0, 0);
        }

        if (pass == 0) {
            // pack nf0..3 to bf16 pairs; frees the 64 AGPR for pass 1
#pragma unroll
            for (int j = 0; j < 16; ++j) {
                ph0[j] = f2bf(acc[0][j]) | (f2bf(acc[1][j]) << 16);
                ph1[j] = f2bf(acc[2][j]) | (f2bf(acc[3][j]) << 16);
            }
        }
    }

    // ---- epilogue: LayerNorm (row lives in one lane-half); NT stores
    // (bypass L2 write-allocate RFO).
    float gv[8], bv[8];
#pragma unroll
    for (int nf = 0; nf < 8; ++nf) {
        int c = nf * 32 + l31;
        gv[nf] = gamma[c]; bv[nf] = beta[c];
    }
#pragma unroll
    for (int j = 0; j < 16; ++j) {
        const int rl = (j & 3) + ((j >> 2) << 3) + (h << 2);
        float hv[8];
        hv[0] = bclo(ph0[j]); hv[1] = bchi(ph0[j]);
        hv[2] = bclo(ph1[j]); hv[3] = bchi(ph1[j]);
        hv[4] = acc[0][j];    hv[5] = acc[1][j];
        hv[6] = acc[2][j];    hv[7] = acc[3][j];
        float hsum = 0.f, hsq = 0.f;
#pragma unroll
        for (int nf = 0; nf < 8; ++nf) { hsum += hv[nf]; hsq += hv[nf] * hv[nf]; }
#pragma unroll
        for (int d = 1; d < 32; d <<= 1) {
            hsum += __shfl_xor(hsum, d, 64);
            hsq  += __shfl_xor(hsq,  d, 64);
        }
        float mu  = hsum * (1.f / 256.f);
        float var = hsq * (1.f / 256.f) - mu * mu;
        float rs  = rsqrtf(var + EPS);
        float* orow = out + (size_t)(R + rl) * 256 + l31;
#pragma unroll
        for (int nf = 0; nf < 8; ++nf)
            __builtin_nontemporal_store((hv[nf] - mu) * rs * gv[nf] + bv[nf],
                                        orow + nf * 32);
    }
}

extern "C" void kernel_launch(void* const* d_in, const int* in_sizes, int n_in,
                              void* d_out, int out_size, void* d_ws, size_t ws_size,
                              hipStream_t stream) {
    const int*   z     = (const int*)d_in[0];
    const float* x     = (const float*)d_in[1];
    const float* emb   = (const float*)d_in[2];
    const float* w1    = (const float*)d_in[3];
    const float* b1    = (const float*)d_in[4];
    const float* w2    = (const float*)d_in[5];
    const float* b2    = (const float*)d_in[6];
    const float* gamma = (const float*)d_in[7];
    const float* beta  = (const float*)d_in[8];
    float* out = (float*)d_out;
    const int N = in_sizes[0];

    unsigned short* w2f  = (unsigned short*)d_ws;              // 128 KB
    unsigned*       embp = (unsigned*)((char*)d_ws + 131072);  // 50 KB bf16-pair emb+b2
    unsigned*       w1q  = (unsigned*)((char*)d_ws + 182272);  // 2 KB packed w1/b1

    prep<<<(65536 + 12800 + 256 + 255) / 256, 256, 0, stream>>>(
        w2, emb, b2, w1, b1, w2f, embp, w1q);

    int tiles = N >> 5;                    // one 32-row tile per 64-thread block
    fused_kernel<<<tiles, 64, 0, stream>>>(z, x, w2f, embp, w1q,
                                           gamma, beta, out, N);
}

// Round 12
// 296.366 us; speedup vs baseline: 5.1995x; 5.1995x over previous
//
#include <hip/hip_runtime.h>

#define EPS 1e-5f
#define WAVES 4

typedef __attribute__((ext_vector_type(8)))  short short8;
typedef __attribute__((ext_vector_type(4)))  short short4_t;
typedef __attribute__((ext_vector_type(16))) float f32x16;
typedef __attribute__((ext_vector_type(4)))  float f32x4;
typedef __attribute__((ext_vector_type(4)))  unsigned u32x4;

__device__ inline unsigned f2bf(float f) {
    unsigned u = __builtin_bit_cast(unsigned, f);
    return (u + 0x7fffu + ((u >> 16) & 1u)) >> 16;   // RNE f32->bf16
}

// prep (unchanged from R7): two regions of d_ws
//  [0)      w2f:  bf16 w2 in mfma_f32_32x32x16_bf16 B-frag order
//           w2f[nf*8192 + ks*512 + lane*8 + e] = bf16(w2[ks*16+(lane>>5)*8+e][nf*32+(lane&31)])
//  [131072) embp: (emb + b2) as bf16 pairs: embp[row*128+g*32+c] =
//           pack(bf16(e[row][g*64+c]), bf16(e[row][g*64+32+c]))
__global__ void prep(const float* __restrict__ w2, const float* __restrict__ emb,
                     const float* __restrict__ b2,
                     unsigned short* __restrict__ w2f, unsigned* __restrict__ embp) {
    int idx = blockIdx.x * 256 + threadIdx.x;
    if (idx < 65536) {
        int e    = idx & 7;
        int lane = (idx >> 3) & 63;
        int ks   = (idx >> 9) & 15;
        int nf   = idx >> 13;
        int k    = ks * 16 + ((lane >> 5) << 3) + e;
        int n    = nf * 32 + (lane & 31);
        w2f[idx] = (unsigned short)f2bf(w2[k * 256 + n]);
    } else if (idx < 65536 + 12800) {
        int i   = idx - 65536;
        int row = i >> 7;
        int w   = i & 127;
        int g   = w >> 5;
        int c   = w & 31;
        int clo = g * 64 + c;
        int chi = clo + 32;
        unsigned lo = f2bf(emb[row * 256 + clo] + b2[clo]);
        unsigned hi = f2bf(emb[row * 256 + chi] + b2[chi]);
        embp[i] = lo | (hi << 16);
    }
}

__global__ __launch_bounds__(256, 1) void fused_kernel(
    const int* __restrict__ z, const float* __restrict__ x,
    const float* __restrict__ w1, const float* __restrict__ b1,
    const unsigned short* __restrict__ w2f, const unsigned* __restrict__ embp,
    const float* __restrict__ gamma, const float* __restrict__ beta,
    float* __restrict__ out, int N)
{
    // R7 wave structure, plus the 50KB packed emb table staged in LDS: the
    // gather becomes conflict-free LDS reads (zero HBM gather traffic). One
    // barrier after the table load; everything after is per-wave, barrier-free.
    __shared__ unsigned embs[12800];         // 50KB: (emb+b2) bf16 pairs
    __shared__ char  p_lds[WAVES * 16384];   // per-wave 32x256 bf16 A-tile (swizzled)
    __shared__ float x_lds[WAVES][32][4];
    __shared__ int   z_lds[WAVES][32];

    const int tid  = threadIdx.x;
    const int wave = tid >> 6;
    const int lane = tid & 63;
    const int l31  = lane & 31;
    const int h    = lane >> 5;
    char* pbuf = p_lds + wave * 16384;

    const int tiles = N >> 5;
    const int t = blockIdx.x * WAVES + wave;
    const bool act = (t < tiles);
    const int R = t << 5;

    // per-wave x/z staging (no barrier needed: same-wave producer/consumer)
    if (act && lane < 32) {
        int r = R + lane;
        x_lds[wave][lane][0] = x[r * 3 + 0];
        x_lds[wave][lane][1] = x[r * 3 + 1];
        x_lds[wave][lane][2] = x[r * 3 + 2];
        z_lds[wave][lane]    = z[r];
    }

    // cooperative load of the packed table (coalesced u32x4), then the ONLY barrier
    {
        u32x4*       d = (u32x4*)embs;
        const u32x4* s = (const u32x4*)embp;
        for (int i = tid; i < 3200; i += 256) d[i] = s[i];
    }
    __syncthreads();
    if (!act) return;

    // ---- init acc with (emb+b2) gather from LDS (C/D layout). Per half-wave:
    // 32 lanes read consecutive 128B of one row -> conflict-free; two halves
    // hit different rows -> 2-way (free).
    f32x16 acc[8];
#pragma unroll
    for (int j = 0; j < 16; ++j) {
        const int rl = (j & 3) + ((j >> 2) << 3) + (h << 2);
        const unsigned* er = embs + z_lds[wave][rl] * 128 + l31;
#pragma unroll
        for (int g = 0; g < 4; ++g) {
            unsigned u = er[g * 32];
            acc[2 * g][j]     = __builtin_bit_cast(float, u << 16);
            acc[2 * g + 1][j] = __builtin_bit_cast(float, u & 0xffff0000u);
        }
    }

    // hoisted per-lane weights: this lane computes p columns [lane*4, lane*4+3]
    const int  c0  = lane * 4;
    const f32x4 w1a = *(const f32x4*)(w1 + c0);
    const f32x4 w1b = *(const f32x4*)(w1 + 256 + c0);
    const f32x4 w1c = *(const f32x4*)(w1 + 512 + c0);
    const f32x4 b1v = *(const f32x4*)(b1 + c0);
    float gv[8], bv[8];
#pragma unroll
    for (int nf = 0; nf < 8; ++nf) {
        int c = nf * 32 + l31;
        gv[nf] = gamma[c]; bv[nf] = beta[c];
    }

    // p = silu(x @ w1 + b1) -> bf16 LDS tile, XOR-swizzled rows
#pragma unroll
    for (int r = 0; r < 32; ++r) {
        float x0 = x_lds[wave][r][0];
        float x1 = x_lds[wave][r][1];
        float x2 = x_lds[wave][r][2];
        short4_t pv;
#pragma unroll
        for (int j = 0; j < 4; ++j) {
            float tv = x0 * w1a[j] + x1 * w1b[j] + x2 * w1c[j] + b1v[j];
            float s  = tv * __builtin_amdgcn_rcpf(1.f + __expf(-tv));
            pv[j] = (short)f2bf(s);
        }
        int off = (r * 512 + lane * 8) ^ ((r & 7) << 4);
        *(short4_t*)(pbuf + off) = pv;
    }

    // GEMM: [32,256] @ [256,256] via mfma_f32_32x32x16_bf16 (acc has emb+b2)
#pragma unroll
    for (int ks = 0; ks < 16; ++ks) {
        int aoff = (l31 * 512 + ks * 32 + h * 16) ^ ((l31 & 7) << 4);
        short8 a = *(const short8*)(pbuf + aoff);
        const unsigned short* bp = w2f + ks * 512 + lane * 8;
#pragma unroll
        for (int nf = 0; nf < 8; ++nf) {
            short8 b = *(const short8*)(bp + nf * 8192);
            acc[nf] = __builtin_amdgcn_mfma_f32_32x32x16_bf16(a, b, acc[nf], 0, 0, 0);
        }
    }

    // epilogue: LayerNorm (row lives in one lane-half) ; NT stores
#pragma unroll
    for (int j = 0; j < 16; ++j) {
        const int rl = (j & 3) + ((j >> 2) << 3) + (h << 2);
        float hv[8];
        float hsum = 0.f, hsq = 0.f;
#pragma unroll
        for (int nf = 0; nf < 8; ++nf) {
            float v = acc[nf][j];
            hv[nf] = v; hsum += v; hsq += v * v;
        }
#pragma unroll
        for (int d = 1; d < 32; d <<= 1) {
            hsum += __shfl_xor(hsum, d, 64);
            hsq  += __shfl_xor(hsq,  d, 64);
        }
        float mu  = hsum * (1.f / 256.f);
        float var = hsq * (1.f / 256.f) - mu * mu;
        float rs  = rsqrtf(var + EPS);
        float* orow = out + (size_t)(R + rl) * 256 + l31;
#pragma unroll
        for (int nf = 0; nf < 8; ++nf)
            __builtin_nontemporal_store((hv[nf] - mu) * rs * gv[nf] + bv[nf],
                                        orow + nf * 32);
    }
}

extern "C" void kernel_launch(void* const* d_in, const int* in_sizes, int n_in,
                              void* d_out, int out_size, void* d_ws, size_t ws_size,
                              hipStream_t stream) {
    const int*   z     = (const int*)d_in[0];
    const float* x     = (const float*)d_in[1];
    const float* emb   = (const float*)d_in[2];
    const float* w1    = (const float*)d_in[3];
    const float* b1    = (const float*)d_in[4];
    const float* w2    = (const float*)d_in[5];
    const float* b2    = (const float*)d_in[6];
    const float* gamma = (const float*)d_in[7];
    const float* beta  = (const float*)d_in[8];
    float* out = (float*)d_out;
    const int N = in_sizes[0];

    unsigned short* w2f  = (unsigned short*)d_ws;              // 128 KB
    unsigned*       embp = (unsigned*)((char*)d_ws + 131072);  // 50 KB bf16-pair emb+b2

    prep<<<(65536 + 12800 + 255) / 256, 256, 0, stream>>>(w2, emb, b2, w2f, embp);

    int tiles  = N >> 5;
    int blocks = (tiles + WAVES - 1) / WAVES;  // one tile per wave, one-shot
    fused_kernel<<<blocks, 256, 0, stream>>>(z, x, w1, b1, w2f, embp,
                                             gamma, beta, out, N);
}

// Round 13
// 208.383 us; speedup vs baseline: 7.3948x; 1.4222x over previous
//
#include <hip/hip_runtime.h>

#define EPS 1e-5f

typedef __attribute__((ext_vector_type(8)))  short short8;
typedef __attribute__((ext_vector_type(16))) float f32x16;
typedef __attribute__((ext_vector_type(4)))  unsigned u32x4;

__device__ inline unsigned f2bf(float f) {
    unsigned u = __builtin_bit_cast(unsigned, f);
    return (u + 0x7fffu + ((u >> 16) & 1u)) >> 16;   // RNE f32->bf16
}
__device__ inline float bchi(unsigned u) { return __builtin_bit_cast(float, u & 0xffff0000u); }
__device__ inline float bclo(unsigned u) { return __builtin_bit_cast(float, u << 16); }

// prep: three regions of d_ws
//  [0)      w2f:  bf16 w2 in mfma_f32_32x32x16_bf16 B-frag order
//           w2f[nf*8192 + ks*512 + lane*8 + e] = bf16(w2[ks*16+(lane>>5)*8+e][nf*32+(lane&31)])
//  [131072) embp: (emb + b2) as bf16 pairs: embp[row*128+g*32+c] =
//           pack(bf16(e[row][g*64+c]), bf16(e[row][g*64+32+c]))
//  [182272) w1q:  per-col packed bf16 {w1_0,w1_1},{w1_2,b1}
__global__ void prep(const float* __restrict__ w2, const float* __restrict__ emb,
                     const float* __restrict__ b2, const float* __restrict__ w1,
                     const float* __restrict__ b1,
                     unsigned short* __restrict__ w2f, unsigned* __restrict__ embp,
                     unsigned* __restrict__ w1q) {
    int idx = blockIdx.x * 256 + threadIdx.x;
    if (idx < 65536) {
        int e    = idx & 7;
        int lane = (idx >> 3) & 63;
        int ks   = (idx >> 9) & 15;
        int nf   = idx >> 13;
        int k    = ks * 16 + ((lane >> 5) << 3) + e;
        int n    = nf * 32 + (lane & 31);
        w2f[idx] = (unsigned short)f2bf(w2[k * 256 + n]);
    } else if (idx < 65536 + 12800) {
        int i   = idx - 65536;
        int row = i >> 7;
        int w   = i & 127;
        int g   = w >> 5;
        int c   = w & 31;
        int clo = g * 64 + c;
        int chi = clo + 32;
        unsigned lo = f2bf(emb[row * 256 + clo] + b2[clo]);
        unsigned hi = f2bf(emb[row * 256 + chi] + b2[chi]);
        embp[i] = lo | (hi << 16);
    } else if (idx < 65536 + 12800 + 256) {
        int c = idx - (65536 + 12800);
        w1q[2 * c]     = f2bf(w1[c])       | (f2bf(w1[256 + c]) << 16);
        w1q[2 * c + 1] = f2bf(w1[512 + c]) | (f2bf(b1[c]) << 16);
    }
}

__device__ inline float scol(unsigned u0, unsigned u1, float x0, float x1, float x2) {
    float t = x0 * bclo(u0) + x1 * bchi(u0) + x2 * bclo(u1) + bchi(u1);
    return t * __builtin_amdgcn_rcpf(1.f + __expf(-t));
}

// 512-thread block (8 waves), each wave one 32-row tile. LDS holds ONLY the
// shared tables (emb 50KB + w1 2KB, one copy per CU); silu is computed
// directly in A-fragment layout (no A-tile staging) -> 2 blocks/CU worth of
// waves (8 waves/CU, reg-limited 2/SIMD) with R12's optimal traffic profile.
__global__ __launch_bounds__(512, 2) void fused_kernel(
    const int* __restrict__ z, const float* __restrict__ x,
    const unsigned short* __restrict__ w2f, const unsigned* __restrict__ embp,
    const unsigned* __restrict__ w1qg,
    const float* __restrict__ gamma, const float* __restrict__ beta,
    float* __restrict__ out, int N)
{
    __shared__ unsigned embs[12800];   // 50 KB packed (emb+b2)
    __shared__ unsigned w1s[512];      // 2 KB packed w1/b1

    const int tid  = threadIdx.x;
    const int wave = tid >> 6;
    const int lane = tid & 63;
    const int l31  = lane & 31;
    const int h    = lane >> 5;

    // cooperative table staging, then the only barrier
    {
        u32x4*       d = (u32x4*)embs;
        const u32x4* s = (const u32x4*)embp;
        for (int i = tid; i < 3200; i += 512) d[i] = s[i];
        if (tid < 128) ((u32x4*)w1s)[tid] = ((const u32x4*)w1qg)[tid];
    }
    __syncthreads();

    const int tiles = N >> 5;
    const int t = blockIdx.x * 8 + wave;
    if (t >= tiles) return;            // per-wave exit: no barriers after this
    const int R = t << 5;

    // own-row inputs (lanes l31 / l31+32 duplicate row l31: broadcast-friendly)
    const int   r  = R + l31;
    const int   zo = z[r];
    const float x0 = x[r * 3 + 0];
    const float x1 = x[r * 3 + 1];
    const float x2 = x[r * 3 + 2];

    // ---- init acc with (emb+b2) gather from the LDS table (C/D layout)
    f32x16 acc[8];
#pragma unroll
    for (int j = 0; j < 16; ++j) {
        const int rl = (j & 3) + ((j >> 2) << 3) + (h << 2);
        const int zr = __shfl(zo, rl, 64);
        const unsigned* er = embs + zr * 128 + l31;
#pragma unroll
        for (int g = 0; g < 4; ++g) {
            unsigned u = er[g * 32];
            acc[2 * g][j]     = bclo(u);
            acc[2 * g + 1][j] = bchi(u);
        }
    }

    // ---- K loop: silu computed directly in A-frag layout (row=l31,
    // k=ks*16+h*8+e); w1s reads are half-wave broadcasts (conflict-free).
#pragma unroll
    for (int ks = 0; ks < 16; ++ks) {
        const unsigned* wq = w1s + (ks * 16 + h * 8) * 2;
        u32x4 wqa = *(const u32x4*)(wq);
        u32x4 wqb = *(const u32x4*)(wq + 4);
        u32x4 wqc = *(const u32x4*)(wq + 8);
        u32x4 wqd = *(const u32x4*)(wq + 12);
        u32x4 av;
        av[0] = f2bf(scol(wqa[0], wqa[1], x0, x1, x2)) |
               (f2bf(scol(wqa[2], wqa[3], x0, x1, x2)) << 16);
        av[1] = f2bf(scol(wqb[0], wqb[1], x0, x1, x2)) |
               (f2bf(scol(wqb[2], wqb[3], x0, x1, x2)) << 16);
        av[2] = f2bf(scol(wqc[0], wqc[1], x0, x1, x2)) |
               (f2bf(scol(wqc[2], wqc[3], x0, x1, x2)) << 16);
        av[3] = f2bf(scol(wqd[0], wqd[1], x0, x1, x2)) |
               (f2bf(scol(wqd[2], wqd[3], x0, x1, x2)) << 16);
        short8 a = __builtin_bit_cast(short8, av);

        const unsigned short* bp = w2f + ks * 512 + lane * 8;
#pragma unroll
        for (int nf = 0; nf < 8; ++nf) {
            short8 b = *(const short8*)(bp + nf * 8192);
            acc[nf] = __builtin_amdgcn_mfma_f32_32x32x16_bf16(a, b, acc[nf], 0, 0, 0);
        }
    }

    // ---- epilogue: LayerNorm (row lives in one lane-half); NT stores
    float gv[8], bv[8];
#pragma unroll
    for (int nf = 0; nf < 8; ++nf) {
        int c = nf * 32 + l31;
        gv[nf] = gamma[c]; bv[nf] = beta[c];
    }
#pragma unroll
    for (int j = 0; j < 16; ++j) {
        const int rl = (j & 3) + ((j >> 2) << 3) + (h << 2);
        float hv[8];
        float hsum = 0.f, hsq = 0.f;
#pragma unroll
        for (int nf = 0; nf < 8; ++nf) {
            float v = acc[nf][j];
            hv[nf] = v; hsum += v; hsq += v * v;
        }
#pragma unroll
        for (int d = 1; d < 32; d <<= 1) {
            hsum += __shfl_xor(hsum, d, 64);
            hsq  += __shfl_xor(hsq,  d, 64);
        }
        float mu  = hsum * (1.f / 256.f);
        float var = hsq * (1.f / 256.f) - mu * mu;
        float rs  = rsqrtf(var + EPS);
        float* orow = out + (size_t)(R + rl) * 256 + l31;
#pragma unroll
        for (int nf = 0; nf < 8; ++nf)
            __builtin_nontemporal_store((hv[nf] - mu) * rs * gv[nf] + bv[nf],
                                        orow + nf * 32);
    }
}

extern "C" void kernel_launch(void* const* d_in, const int* in_sizes, int n_in,
                              void* d_out, int out_size, void* d_ws, size_t ws_size,
                              hipStream_t stream) {
    const int*   z     = (const int*)d_in[0];
    const float* x     = (const float*)d_in[1];
    const float* emb   = (const float*)d_in[2];
    const float* w1    = (const float*)d_in[3];
    const float* b1    = (const float*)d_in[4];
    const float* w2    = (const float*)d_in[5];
    const float* b2    = (const float*)d_in[6];
    const float* gamma = (const float*)d_in[7];
    const float* beta  = (const float*)d_in[8];
    float* out = (float*)d_out;
    const int N = in_sizes[0];

    unsigned short* w2f  = (unsigned short*)d_ws;              // 128 KB
    unsigned*       embp = (unsigned*)((char*)d_ws + 131072);  // 50 KB bf16-pair emb+b2
    unsigned*       w1q  = (unsigned*)((char*)d_ws + 182272);  // 2 KB packed w1/b1

    prep<<<(65536 + 12800 + 256 + 255) / 256, 256, 0, stream>>>(
        w2, emb, b2, w1, b1, w2f, embp, w1q);

    int tiles  = N >> 5;
    int blocks = (tiles + 7) / 8;          // 8 waves/block, one 32-row tile each
    fused_kernel<<<blocks, 512, 0, stream>>>(z, x, w2f, embp, w1q,
                                             gamma, beta, out, N);
}

// Round 14
// 207.044 us; speedup vs baseline: 7.4427x; 1.0065x over previous
//
#include <hip/hip_runtime.h>

#define EPS 1e-5f

typedef __attribute__((ext_vector_type(8)))  short short8;
typedef __attribute__((ext_vector_type(16))) float f32x16;
typedef __attribute__((ext_vector_type(4)))  unsigned u32x4;

__device__ inline unsigned f2bf(float f) {
    unsigned u = __builtin_bit_cast(unsigned, f);
    return (u + 0x7fffu + ((u >> 16) & 1u)) >> 16;   // RNE f32->bf16
}
__device__ inline float bchi(unsigned u) { return __builtin_bit_cast(float, u & 0xffff0000u); }
__device__ inline float bclo(unsigned u) { return __builtin_bit_cast(float, u << 16); }

// prep: three regions of d_ws
//  [0)      w2f:  bf16 w2 in mfma_f32_32x32x16_bf16 B-frag order
//           w2f[nf*8192 + ks*512 + lane*8 + e] = bf16(w2[ks*16+(lane>>5)*8+e][nf*32+(lane&31)])
//  [131072) embp: (emb + b2) as bf16 pairs: embp[row*128+g*32+c] =
//           pack(bf16(e[row][g*64+c]), bf16(e[row][g*64+32+c]))
//  [182272) w1q:  per-col packed bf16 {w1_0,w1_1},{w1_2,b1}
__global__ void prep(const float* __restrict__ w2, const float* __restrict__ emb,
                     const float* __restrict__ b2, const float* __restrict__ w1,
                     const float* __restrict__ b1,
                     unsigned short* __restrict__ w2f, unsigned* __restrict__ embp,
                     unsigned* __restrict__ w1q) {
    int idx = blockIdx.x * 256 + threadIdx.x;
    if (idx < 65536) {
        int e    = idx & 7;
        int lane = (idx >> 3) & 63;
        int ks   = (idx >> 9) & 15;
        int nf   = idx >> 13;
        int k    = ks * 16 + ((lane >> 5) << 3) + e;
        int n    = nf * 32 + (lane & 31);
        w2f[idx] = (unsigned short)f2bf(w2[k * 256 + n]);
    } else if (idx < 65536 + 12800) {
        int i   = idx - 65536;
        int row = i >> 7;
        int w   = i & 127;
        int g   = w >> 5;
        int c   = w & 31;
        int clo = g * 64 + c;
        int chi = clo + 32;
        unsigned lo = f2bf(emb[row * 256 + clo] + b2[clo]);
        unsigned hi = f2bf(emb[row * 256 + chi] + b2[chi]);
        embp[i] = lo | (hi << 16);
    } else if (idx < 65536 + 12800 + 256) {
        int c = idx - (65536 + 12800);
        w1q[2 * c]     = f2bf(w1[c])       | (f2bf(w1[256 + c]) << 16);
        w1q[2 * c + 1] = f2bf(w1[512 + c]) | (f2bf(b1[c]) << 16);
    }
}

__device__ inline float scol(unsigned u0, unsigned u1, float x0, float x1, float x2) {
    float t = x0 * bclo(u0) + x1 * bchi(u0) + x2 * bclo(u1) + bchi(u1);
    return t * __builtin_amdgcn_rcpf(1.f + __expf(-t));
}

// 512-thread block (8 waves), one 32-row tile per wave. LDS holds only the
// shared tables (52KB -> 2 blocks/CU, 16 waves/CU). PHASE-SEPARATED: all 16
// A-fragments computed into registers first (64 VGPR), then a pure
// B-load+MFMA loop — R7's decoupling without its A-tile LDS or gather traffic.
__global__ __launch_bounds__(512, 2) void fused_kernel(
    const int* __restrict__ z, const float* __restrict__ x,
    const unsigned short* __restrict__ w2f, const unsigned* __restrict__ embp,
    const unsigned* __restrict__ w1qg,
    const float* __restrict__ gamma, const float* __restrict__ beta,
    float* __restrict__ out, int N)
{
    __shared__ unsigned embs[12800];   // 50 KB packed (emb+b2)
    __shared__ unsigned w1s[512];      // 2 KB packed w1/b1

    const int tid  = threadIdx.x;
    const int wave = tid >> 6;
    const int lane = tid & 63;
    const int l31  = lane & 31;
    const int h    = lane >> 5;

    // cooperative table staging, then the only barrier
    {
        u32x4*       d = (u32x4*)embs;
        const u32x4* s = (const u32x4*)embp;
        for (int i = tid; i < 3200; i += 512) d[i] = s[i];
        if (tid < 128) ((u32x4*)w1s)[tid] = ((const u32x4*)w1qg)[tid];
    }
    __syncthreads();

    const int tiles = N >> 5;
    const int t = blockIdx.x * 8 + wave;
    if (t >= tiles) return;            // per-wave exit: no barriers after this
    const int R = t << 5;

    // own-row inputs (lanes l31 / l31+32 duplicate row l31)
    const int   r  = R + l31;
    const int   zo = z[r];
    const float x0 = x[r * 3 + 0];
    const float x1 = x[r * 3 + 1];
    const float x2 = x[r * 3 + 2];

    // ---- init acc with (emb+b2) gather from the LDS table (C/D layout)
    f32x16 acc[8];
#pragma unroll
    for (int j = 0; j < 16; ++j) {
        const int rl = (j & 3) + ((j >> 2) << 3) + (h << 2);
        const int zr = __shfl(zo, rl, 64);
        const unsigned* er = embs + zr * 128 + l31;
#pragma unroll
        for (int g = 0; g < 4; ++g) {
            unsigned u = er[g * 32];
            acc[2 * g][j]     = bclo(u);
            acc[2 * g + 1][j] = bchi(u);
        }
    }

    // ---- PHASE 1: all 16 A-fragments into registers (row=l31, k=ks*16+h*8+e)
    short8 af[16];
#pragma unroll
    for (int ks = 0; ks < 16; ++ks) {
        const unsigned* wq = w1s + (ks * 16 + h * 8) * 2;
        u32x4 wqa = *(const u32x4*)(wq);
        u32x4 wqb = *(const u32x4*)(wq + 4);
        u32x4 wqc = *(const u32x4*)(wq + 8);
        u32x4 wqd = *(const u32x4*)(wq + 12);
        u32x4 av;
        av[0] = f2bf(scol(wqa[0], wqa[1], x0, x1, x2)) |
               (f2bf(scol(wqa[2], wqa[3], x0, x1, x2)) << 16);
        av[1] = f2bf(scol(wqb[0], wqb[1], x0, x1, x2)) |
               (f2bf(scol(wqb[2], wqb[3], x0, x1, x2)) << 16);
        av[2] = f2bf(scol(wqc[0], wqc[1], x0, x1, x2)) |
               (f2bf(scol(wqc[2], wqc[3], x0, x1, x2)) << 16);
        av[3] = f2bf(scol(wqd[0], wqd[1], x0, x1, x2)) |
               (f2bf(scol(wqd[2], wqd[3], x0, x1, x2)) << 16);
        af[ks] = __builtin_bit_cast(short8, av);
    }

    // ---- PHASE 2: pure B-load + MFMA loop (no VALU chain in the way;
    // compiler free to pipeline B loads across ks)
#pragma unroll
    for (int ks = 0; ks < 16; ++ks) {
        const unsigned short* bp = w2f + ks * 512 + lane * 8;
#pragma unroll
        for (int nf = 0; nf < 8; ++nf) {
            short8 b = *(const short8*)(bp + nf * 8192);
            acc[nf] = __builtin_amdgcn_mfma_f32_32x32x16_bf16(af[ks], b, acc[nf], 0, 0, 0);
        }
    }

    // ---- epilogue: LayerNorm (row lives in one lane-half); NT stores
    float gv[8], bv[8];
#pragma unroll
    for (int nf = 0; nf < 8; ++nf) {
        int c = nf * 32 + l31;
        gv[nf] = gamma[c]; bv[nf] = beta[c];
    }
#pragma unroll
    for (int j = 0; j < 16; ++j) {
        const int rl = (j & 3) + ((j >> 2) << 3) + (h << 2);
        float hv[8];
        float hsum = 0.f, hsq = 0.f;
#pragma unroll
        for (int nf = 0; nf < 8; ++nf) {
            float v = acc[nf][j];
            hv[nf] = v; hsum += v; hsq += v * v;
        }
#pragma unroll
        for (int d = 1; d < 32; d <<= 1) {
            hsum += __shfl_xor(hsum, d, 64);
            hsq  += __shfl_xor(hsq,  d, 64);
        }
        float mu  = hsum * (1.f / 256.f);
        float var = hsq * (1.f / 256.f) - mu * mu;
        float rs  = rsqrtf(var + EPS);
        float* orow = out + (size_t)(R + rl) * 256 + l31;
#pragma unroll
        for (int nf = 0; nf < 8; ++nf)
            __builtin_nontemporal_store((hv[nf] - mu) * rs * gv[nf] + bv[nf],
                                        orow + nf * 32);
    }
}

extern "C" void kernel_launch(void* const* d_in, const int* in_sizes, int n_in,
                              void* d_out, int out_size, void* d_ws, size_t ws_size,
                              hipStream_t stream) {
    const int*   z     = (const int*)d_in[0];
    const float* x     = (const float*)d_in[1];
    const float* emb   = (const float*)d_in[2];
    const float* w1    = (const float*)d_in[3];
    const float* b1    = (const float*)d_in[4];
    const float* w2    = (const float*)d_in[5];
    const float* b2    = (const float*)d_in[6];
    const float* gamma = (const float*)d_in[7];
    const float* beta  = (const float*)d_in[8];
    float* out = (float*)d_out;
    const int N = in_sizes[0];

    unsigned short* w2f  = (unsigned short*)d_ws;              // 128 KB
    unsigned*       embp = (unsigned*)((char*)d_ws + 131072);  // 50 KB bf16-pair emb+b2
    unsigned*       w1q  = (unsigned*)((char*)d_ws + 182272);  // 2 KB packed w1/b1

    prep<<<(65536 + 12800 + 256 + 255) / 256, 256, 0, stream>>>(
        w2, emb, b2, w1, b1, w2f, embp, w1q);

    int tiles  = N >> 5;
    int blocks = (tiles + 7) / 8;          // 8 waves/block, one 32-row tile each
    fused_kernel<<<blocks, 512, 0, stream>>>(z, x, w2f, embp, w1q,
                                             gamma, beta, out, N);
}